// Round 2
// baseline (508.889 us; speedup 1.0000x reference)
//
#include <hip/hip_runtime.h>
#include <cmath>

namespace {

constexpr float kScale = 0.08838834764831845f;  // 128^-0.5

__device__ __forceinline__ int voxel_row(int p, int pix) {
  int pd = p >> 6, ph = (p >> 3) & 7, pw = p & 7;
  int iz = pix >> 4, iy = (pix >> 2) & 3, ix = pix & 3;
  return (((pd * 4 + iz) * 32 + (ph * 4 + iy)) * 32 + (pw * 4 + ix));
}

__device__ __forceinline__ void fma4(float4& a, float s, float4 b) {
  a.x = fmaf(s, b.x, a.x); a.y = fmaf(s, b.y, a.y);
  a.z = fmaf(s, b.z, a.z); a.w = fmaf(s, b.w, a.w);
}

// ---------------- QKV projection: (32768 x 128) @ (128 x 384) ----------------
// grid (3, 512): blockIdx.x = col tile (q/k/v), blockIdx.y = window.
__global__ __launch_bounds__(256) void k_qkv(
    const float* __restrict__ x, const float* __restrict__ w,
    const float* __restrict__ bias, float* __restrict__ q,
    float* __restrict__ k, float* __restrict__ v) {
  __shared__ float ldsA[64][132];  // [pix][k], pad 132 -> 2-way conflicts only
  const int ct = blockIdx.x, p = blockIdx.y, t = threadIdx.x;
#pragma unroll
  for (int i = 0; i < 8; ++i) {
    int idx = t + i * 256;          // 64 pix * 32 float4
    int pix = idx >> 5, k4 = idx & 31;
    float4 val = *(const float4*)(x + (size_t)voxel_row(p, pix) * 128 + k4 * 4);
    *(float4*)(&ldsA[pix][k4 * 4]) = val;
  }
  __syncthreads();
  const int cg = t & 15, rg = t >> 4;  // cols cg*8..+7, rows rg*4..+3
  const float* wcol = w + ct * 128 + cg * 8;
  float4 acc[4][2];
#pragma unroll
  for (int r = 0; r < 4; ++r) {
    acc[r][0] = float4{0.f, 0.f, 0.f, 0.f};
    acc[r][1] = float4{0.f, 0.f, 0.f, 0.f};
  }
  for (int kk = 0; kk < 128; kk += 4) {
    float4 a[4];
#pragma unroll
    for (int r = 0; r < 4; ++r) a[r] = *(const float4*)(&ldsA[rg * 4 + r][kk]);
#pragma unroll
    for (int dk = 0; dk < 4; ++dk) {
      float4 w0 = *(const float4*)(wcol + (kk + dk) * 384);
      float4 w1 = *(const float4*)(wcol + (kk + dk) * 384 + 4);
#pragma unroll
      for (int r = 0; r < 4; ++r) {
        float av = (&a[r].x)[dk];
        fma4(acc[r][0], av, w0);
        fma4(acc[r][1], av, w1);
      }
    }
  }
  float* dst = (ct == 0) ? q : (ct == 1) ? k : v;
  float4 b0 = *(const float4*)(bias + ct * 128 + cg * 8);
  float4 b1 = *(const float4*)(bias + ct * 128 + cg * 8 + 4);
#pragma unroll
  for (int r = 0; r < 4; ++r) {
    float4 o0 = acc[r][0], o1 = acc[r][1];
    o0.x += b0.x; o0.y += b0.y; o0.z += b0.z; o0.w += b0.w;
    o1.x += b1.x; o1.y += b1.y; o1.z += b1.z; o1.w += b1.w;
    size_t row = (size_t)(p * 64 + rg * 4 + r) * 128 + cg * 8;
    *(float4*)(dst + row) = o0;
    *(float4*)(dst + row + 4) = o1;
  }
}

// ---------------- window means ----------------
__global__ __launch_bounds__(128) void k_means(
    const float* __restrict__ q, const float* __restrict__ k,
    float* __restrict__ qwin, float* __restrict__ kwin) {
  const int p = blockIdx.x, c = threadIdx.x;
  float sq = 0.f, sk = 0.f;
  for (int pix = 0; pix < 64; ++pix) {
    sq += q[((size_t)p * 64 + pix) * 128 + c];
    sk += k[((size_t)p * 64 + pix) * 128 + c];
  }
  qwin[p * 128 + c] = sq * (1.f / 64.f);
  kwin[p * 128 + c] = sk * (1.f / 64.f);
}

// ---------------- routing: logits row + top-4 ----------------
__global__ __launch_bounds__(256) void k_route(
    const float* __restrict__ qwin, const float* __restrict__ kwin,
    int* __restrict__ ridx) {
  __shared__ float qs[128];
  __shared__ float lg[512];
  __shared__ float rv[256];
  __shared__ int ri[256];
  const int p = blockIdx.x, t = threadIdx.x;
  if (t < 32) *(float4*)(&qs[t * 4]) = *(const float4*)(qwin + p * 128 + t * 4);
  __syncthreads();
  for (int jj = t; jj < 512; jj += 256) {
    const float* kr = kwin + (size_t)jj * 128;
    float s = 0.f;
    for (int c = 0; c < 128; c += 4) {
      float4 k4 = *(const float4*)(kr + c);
      float4 q4 = *(const float4*)(qs + c);
      s += q4.x * k4.x + q4.y * k4.y + q4.z * k4.z + q4.w * k4.w;
    }
    lg[jj] = s;  // positive scale doesn't change top-k set
  }
  __syncthreads();
  for (int sel = 0; sel < 4; ++sel) {
    float bv = lg[t];
    int bi = t;
    float v2 = lg[t + 256];
    if (v2 > bv) { bv = v2; bi = t + 256; }
    rv[t] = bv; ri[t] = bi;
    __syncthreads();
    for (int off = 128; off > 0; off >>= 1) {
      if (t < off && rv[t + off] > rv[t]) { rv[t] = rv[t + off]; ri[t] = ri[t + off]; }
      __syncthreads();
    }
    if (t == 0) { ridx[p * 4 + sel] = ri[0]; lg[ri[0]] = -INFINITY; }
    __syncthreads();
  }
}

// ---------------- attention per (head, window) ----------------
// writes softmax(QK^T)V into the `out` region at spatial layout.
__global__ __launch_bounds__(256) void k_attn(
    const float* __restrict__ q, const float* __restrict__ k,
    const float* __restrict__ v, const int* __restrict__ ridx,
    float* __restrict__ ao) {
  __shared__ float ldsQ[64][20];   // stride 20: conflict-free-ish
  __shared__ float ldsK[256][20];
  __shared__ float ldsV[256][20];
  __shared__ int widx[4];
  const int h = blockIdx.x, p = blockIdx.y, t = threadIdx.x;
  if (t < 4) widx[t] = ridx[p * 4 + t];
  __syncthreads();
  {  // stage Q (scaled)
    int pix = t >> 2, c4 = t & 3;
    float4 qv = *(const float4*)(q + ((size_t)p * 64 + pix) * 128 + h * 16 + c4 * 4);
    qv.x *= kScale; qv.y *= kScale; qv.z *= kScale; qv.w *= kScale;
    *(float4*)(&ldsQ[pix][c4 * 4]) = qv;
  }
#pragma unroll
  for (int i = 0; i < 4; ++i) {  // stage K_sel, V_sel
    int idx = t + i * 256;
    int j = idx >> 2, c4 = idx & 3;
    size_t src = ((size_t)widx[j >> 6] * 64 + (j & 63)) * 128 + h * 16 + c4 * 4;
    *(float4*)(&ldsK[j][c4 * 4]) = *(const float4*)(k + src);
    *(float4*)(&ldsV[j][c4 * 4]) = *(const float4*)(v + src);
  }
  __syncthreads();

  const int jg = t & 15, rg = t >> 4;  // keys jg*16..+15, rows rg*4..+3
  float s[4][16];
#pragma unroll
  for (int r = 0; r < 4; ++r)
#pragma unroll
    for (int jj = 0; jj < 16; ++jj) s[r][jj] = 0.f;
#pragma unroll
  for (int c4 = 0; c4 < 4; ++c4) {
    float4 qr[4];
#pragma unroll
    for (int r = 0; r < 4; ++r) qr[r] = *(const float4*)(&ldsQ[rg * 4 + r][c4 * 4]);
#pragma unroll
    for (int jj = 0; jj < 16; ++jj) {
      float4 kf = *(const float4*)(&ldsK[jg * 16 + jj][c4 * 4]);
#pragma unroll
      for (int r = 0; r < 4; ++r)
        s[r][jj] += qr[r].x * kf.x + qr[r].y * kf.y + qr[r].z * kf.z + qr[r].w * kf.w;
    }
  }
  // row softmax over 256 keys (16 threads per row, width-16 shuffles)
  float l[4];
#pragma unroll
  for (int r = 0; r < 4; ++r) {
    float mm = s[r][0];
#pragma unroll
    for (int jj = 1; jj < 16; ++jj) mm = fmaxf(mm, s[r][jj]);
#pragma unroll
    for (int mask = 1; mask < 16; mask <<= 1) mm = fmaxf(mm, __shfl_xor(mm, mask, 16));
    float ll = 0.f;
#pragma unroll
    for (int jj = 0; jj < 16; ++jj) {
      s[r][jj] = __expf(s[r][jj] - mm);
      ll += s[r][jj];
    }
#pragma unroll
    for (int mask = 1; mask < 16; mask <<= 1) ll += __shfl_xor(ll, mask, 16);
    l[r] = ll;
  }
  // PV
  float4 acc[4][4];
#pragma unroll
  for (int r = 0; r < 4; ++r)
#pragma unroll
    for (int c4 = 0; c4 < 4; ++c4) acc[r][c4] = float4{0.f, 0.f, 0.f, 0.f};
#pragma unroll
  for (int jj = 0; jj < 16; ++jj) {
#pragma unroll
    for (int c4 = 0; c4 < 4; ++c4) {
      float4 vf = *(const float4*)(&ldsV[jg * 16 + jj][c4 * 4]);
#pragma unroll
      for (int r = 0; r < 4; ++r) fma4(acc[r][c4], s[r][jj], vf);
    }
  }
  // reduce partial PV + write
#pragma unroll
  for (int r = 0; r < 4; ++r) {
    float inv = 1.f / l[r];
#pragma unroll
    for (int c4 = 0; c4 < 4; ++c4) {
      float4 a4 = acc[r][c4];
#pragma unroll
      for (int mask = 1; mask < 16; mask <<= 1) {
        a4.x += __shfl_xor(a4.x, mask, 16);
        a4.y += __shfl_xor(a4.y, mask, 16);
        a4.z += __shfl_xor(a4.z, mask, 16);
        a4.w += __shfl_xor(a4.w, mask, 16);
      }
      if (jg == 0) {
        a4.x *= inv; a4.y *= inv; a4.z *= inv; a4.w *= inv;
        size_t row = (size_t)voxel_row(p, rg * 4 + r) * 128 + h * 16 + c4 * 4;
        *(float4*)(ao + row) = a4;
      }
    }
  }
}

// ---------------- output projection, in-place on the `out` region ----------------
__global__ __launch_bounds__(256) void k_proj(
    float* io, const float* __restrict__ w, const float* __restrict__ bias) {
  __shared__ float ldsA[64][132];
  const int p = blockIdx.x, t = threadIdx.x;
#pragma unroll
  for (int i = 0; i < 8; ++i) {
    int idx = t + i * 256;
    int pix = idx >> 5, k4 = idx & 31;
    *(float4*)(&ldsA[pix][k4 * 4]) =
        *(const float4*)(io + (size_t)voxel_row(p, pix) * 128 + k4 * 4);
  }
  __syncthreads();
  const int cg = t & 15, rg = t >> 4;
  const float* wcol = w + cg * 8;
  float4 acc[4][2];
#pragma unroll
  for (int r = 0; r < 4; ++r) {
    acc[r][0] = float4{0.f, 0.f, 0.f, 0.f};
    acc[r][1] = float4{0.f, 0.f, 0.f, 0.f};
  }
  for (int kk = 0; kk < 128; kk += 4) {
    float4 a[4];
#pragma unroll
    for (int r = 0; r < 4; ++r) a[r] = *(const float4*)(&ldsA[rg * 4 + r][kk]);
#pragma unroll
    for (int dk = 0; dk < 4; ++dk) {
      float4 w0 = *(const float4*)(wcol + (kk + dk) * 128);
      float4 w1 = *(const float4*)(wcol + (kk + dk) * 128 + 4);
#pragma unroll
      for (int r = 0; r < 4; ++r) {
        float av = (&a[r].x)[dk];
        fma4(acc[r][0], av, w0);
        fma4(acc[r][1], av, w1);
      }
    }
  }
  float4 b0 = *(const float4*)(bias + cg * 8);
  float4 b1 = *(const float4*)(bias + cg * 8 + 4);
#pragma unroll
  for (int r = 0; r < 4; ++r) {
    float4 o0 = acc[r][0], o1 = acc[r][1];
    o0.x += b0.x; o0.y += b0.y; o0.z += b0.z; o0.w += b0.w;
    o1.x += b1.x; o1.y += b1.y; o1.z += b1.z; o1.w += b1.w;
    size_t row = (size_t)voxel_row(p, rg * 4 + r) * 128 + cg * 8;
    *(float4*)(io + row) = o0;
    *(float4*)(io + row + 4) = o1;
  }
}

}  // namespace

extern "C" void kernel_launch(void* const* d_in, const int* in_sizes, int n_in,
                              void* d_out, int out_size, void* d_ws, size_t ws_size,
                              hipStream_t stream) {
  (void)in_sizes; (void)n_in; (void)out_size; (void)ws_size;
  const float* x = (const float*)d_in[0];
  const float* w_qkv = (const float*)d_in[1];
  const float* b_qkv = (const float*)d_in[2];
  const float* w_o = (const float*)d_in[3];
  const float* b_o = (const float*)d_in[4];

  float* out = (float*)d_out;
  float* q = out + 4194304;
  float* k = q + 4194304;
  float* v = k + 4194304;

  float* qwin = (float*)d_ws;           // 512*128 f32
  float* kwin = qwin + 512 * 128;       // 512*128 f32
  int* ridx = (int*)(kwin + 512 * 128); // 512*4 i32

  k_qkv<<<dim3(3, 512), 256, 0, stream>>>(x, w_qkv, b_qkv, q, k, v);
  k_means<<<512, 128, 0, stream>>>(q, k, qwin, kwin);
  k_route<<<512, 256, 0, stream>>>(qwin, kwin, ridx);
  k_attn<<<dim3(8, 512), 256, 0, stream>>>(q, k, v, ridx, out);
  k_proj<<<512, 256, 0, stream>>>(out, w_o, b_o);
}

// Round 3
// 339.461 us; speedup vs baseline: 1.4991x; 1.4991x over previous
//
#include <hip/hip_runtime.h>
#include <cmath>

namespace {

constexpr float kScale = 0.08838834764831845f;  // 128^-0.5

__device__ __forceinline__ int voxel_row(int p, int pix) {
  int pd = p >> 6, ph = (p >> 3) & 7, pw = p & 7;
  int iz = pix >> 4, iy = (pix >> 2) & 3, ix = pix & 3;
  return (((pd * 4 + iz) * 32 + (ph * 4 + iy)) * 32 + (pw * 4 + ix));
}

__device__ __forceinline__ void fma4(float4& a, float s, float4 b) {
  a.x = fmaf(s, b.x, a.x); a.y = fmaf(s, b.y, a.y);
  a.z = fmaf(s, b.z, a.z); a.w = fmaf(s, b.w, a.w);
}

__device__ __forceinline__ float dot4(float4 a, float4 b) {
  return a.x * b.x + a.y * b.y + a.z * b.z + a.w * b.w;
}

// ---------------- QKV projection: (32768 x 128) @ (128 x 384) ----------------
__global__ __launch_bounds__(256) void k_qkv(
    const float* __restrict__ x, const float* __restrict__ w,
    const float* __restrict__ bias, float* __restrict__ q,
    float* __restrict__ k, float* __restrict__ v) {
  __shared__ float ldsA[64][132];
  const int ct = blockIdx.x, p = blockIdx.y, t = threadIdx.x;
#pragma unroll
  for (int i = 0; i < 8; ++i) {
    int idx = t + i * 256;
    int pix = idx >> 5, k4 = idx & 31;
    float4 val = *(const float4*)(x + (size_t)voxel_row(p, pix) * 128 + k4 * 4);
    *(float4*)(&ldsA[pix][k4 * 4]) = val;
  }
  __syncthreads();
  const int cg = t & 15, rg = t >> 4;
  const float* wcol = w + ct * 128 + cg * 8;
  float4 acc[4][2];
#pragma unroll
  for (int r = 0; r < 4; ++r) {
    acc[r][0] = float4{0.f, 0.f, 0.f, 0.f};
    acc[r][1] = float4{0.f, 0.f, 0.f, 0.f};
  }
  for (int kk = 0; kk < 128; kk += 4) {
    float4 a[4];
#pragma unroll
    for (int r = 0; r < 4; ++r) a[r] = *(const float4*)(&ldsA[rg * 4 + r][kk]);
#pragma unroll
    for (int dk = 0; dk < 4; ++dk) {
      float4 w0 = *(const float4*)(wcol + (kk + dk) * 384);
      float4 w1 = *(const float4*)(wcol + (kk + dk) * 384 + 4);
#pragma unroll
      for (int r = 0; r < 4; ++r) {
        float av = (&a[r].x)[dk];
        fma4(acc[r][0], av, w0);
        fma4(acc[r][1], av, w1);
      }
    }
  }
  float* dst = (ct == 0) ? q : (ct == 1) ? k : v;
  float4 b0 = *(const float4*)(bias + ct * 128 + cg * 8);
  float4 b1 = *(const float4*)(bias + ct * 128 + cg * 8 + 4);
#pragma unroll
  for (int r = 0; r < 4; ++r) {
    float4 o0 = acc[r][0], o1 = acc[r][1];
    o0.x += b0.x; o0.y += b0.y; o0.z += b0.z; o0.w += b0.w;
    o1.x += b1.x; o1.y += b1.y; o1.z += b1.z; o1.w += b1.w;
    size_t row = (size_t)(p * 64 + rg * 4 + r) * 128 + cg * 8;
    *(float4*)(dst + row) = o0;
    *(float4*)(dst + row + 4) = o1;
  }
}

// ---------------- window means ----------------
__global__ __launch_bounds__(128) void k_means(
    const float* __restrict__ q, const float* __restrict__ k,
    float* __restrict__ qwin, float* __restrict__ kwin) {
  const int p = blockIdx.x, c = threadIdx.x;
  float sq = 0.f, sk = 0.f;
  for (int pix = 0; pix < 64; ++pix) {
    sq += q[((size_t)p * 64 + pix) * 128 + c];
    sk += k[((size_t)p * 64 + pix) * 128 + c];
  }
  qwin[p * 128 + c] = sq * (1.f / 64.f);
  kwin[p * 128 + c] = sk * (1.f / 64.f);
}

// ---------------- routing: logits row + top-4 ----------------
__global__ __launch_bounds__(256) void k_route(
    const float* __restrict__ qwin, const float* __restrict__ kwin,
    int* __restrict__ ridx) {
  __shared__ float qs[128];
  __shared__ float lg[512];
  __shared__ float rv[256];
  __shared__ int ri[256];
  const int p = blockIdx.x, t = threadIdx.x;
  if (t < 32) *(float4*)(&qs[t * 4]) = *(const float4*)(qwin + p * 128 + t * 4);
  __syncthreads();
  for (int jj = t; jj < 512; jj += 256) {
    const float* kr = kwin + (size_t)jj * 128;
    float s = 0.f;
    for (int c = 0; c < 128; c += 4) {
      float4 k4 = *(const float4*)(kr + c);
      float4 q4 = *(const float4*)(qs + c);
      s += dot4(q4, k4);
    }
    lg[jj] = s;
  }
  __syncthreads();
  for (int sel = 0; sel < 4; ++sel) {
    float bv = lg[t];
    int bi = t;
    float v2 = lg[t + 256];
    if (v2 > bv) { bv = v2; bi = t + 256; }
    rv[t] = bv; ri[t] = bi;
    __syncthreads();
    for (int off = 128; off > 0; off >>= 1) {
      if (t < off && rv[t + off] > rv[t]) { rv[t] = rv[t + off]; ri[t] = ri[t + off]; }
      __syncthreads();
    }
    if (t == 0) { ridx[p * 4 + sel] = ri[0]; lg[ri[0]] = -INFINITY; }
    __syncthreads();
  }
}

// ---------------- attention per (head, window) ----------------
// 4 waves; wave w owns keys [w*64, w*64+64); lane owns q-row = lane.
// All K/V inner-loop LDS reads are wave-uniform (broadcast, conflict-free).
// PV partials reduced via LDS buffer aliasing the dead K tile (stride 20:
// lane*20 mod 32 covers all banks -> conflict-free b128).
__global__ __launch_bounds__(256) void k_attn(
    const float* __restrict__ q, const float* __restrict__ k,
    const float* __restrict__ v, const int* __restrict__ ridx,
    float* __restrict__ ao) {
  __shared__ float ldsKO[256][20];  // K rows; later aliased as oacc[4][64][20]
  __shared__ float ldsV[256][20];
  __shared__ float red_m[4][64];
  __shared__ float red_l[4][64];
  __shared__ int widx[4];
  const int h = blockIdx.x, p = blockIdx.y, t = threadIdx.x;
  const int wave = t >> 6, lane = t & 63;
  if (t < 4) widx[t] = ridx[p * 4 + t];
  __syncthreads();
  // stage K, V (16 floats per row, 4 lanes per row)
#pragma unroll
  for (int i = 0; i < 4; ++i) {
    int idx = t + i * 256;
    int j = idx >> 2, c4 = idx & 3;
    size_t src = ((size_t)widx[j >> 6] * 64 + (j & 63)) * 128 + h * 16 + c4 * 4;
    *(float4*)(&ldsKO[j][c4 * 4]) = *(const float4*)(k + src);
    *(float4*)(&ldsV[j][c4 * 4]) = *(const float4*)(v + src);
  }
  // own Q row -> registers (scaled)
  float4 qr[4];
  {
    const float* qrow = q + ((size_t)p * 64 + lane) * 128 + h * 16;
#pragma unroll
    for (int c4 = 0; c4 < 4; ++c4) {
      qr[c4] = *(const float4*)(qrow + c4 * 4);
      qr[c4].x *= kScale; qr[c4].y *= kScale;
      qr[c4].z *= kScale; qr[c4].w *= kScale;
    }
  }
  __syncthreads();

  const int kbase = wave * 64;
  float s[64];
#pragma unroll 8
  for (int jj = 0; jj < 64; ++jj) {
    const float* kr = &ldsKO[kbase + jj][0];
    float acc = dot4(qr[0], *(const float4*)(kr));
    acc += dot4(qr[1], *(const float4*)(kr + 4));
    acc += dot4(qr[2], *(const float4*)(kr + 8));
    acc += dot4(qr[3], *(const float4*)(kr + 12));
    s[jj] = acc;
  }
  // partial max (registers), cross-wave via LDS
  float m = s[0];
#pragma unroll
  for (int jj = 1; jj < 64; ++jj) m = fmaxf(m, s[jj]);
  red_m[wave][lane] = m;
  __syncthreads();   // also guarantees all K reads done before oacc overwrite
  m = fmaxf(fmaxf(red_m[0][lane], red_m[1][lane]),
            fmaxf(red_m[2][lane], red_m[3][lane]));
  float l = 0.f;
#pragma unroll 8
  for (int jj = 0; jj < 64; ++jj) {
    s[jj] = __expf(s[jj] - m);
    l += s[jj];
  }
  red_l[wave][lane] = l;
  __syncthreads();

  // PV over own chunk (V rows broadcast)
  float4 acc[4];
#pragma unroll
  for (int c4 = 0; c4 < 4; ++c4) acc[c4] = float4{0.f, 0.f, 0.f, 0.f};
#pragma unroll 8
  for (int jj = 0; jj < 64; ++jj) {
    const float* vr = &ldsV[kbase + jj][0];
    float sv = s[jj];
    fma4(acc[0], sv, *(const float4*)(vr));
    fma4(acc[1], sv, *(const float4*)(vr + 4));
    fma4(acc[2], sv, *(const float4*)(vr + 8));
    fma4(acc[3], sv, *(const float4*)(vr + 12));
  }
  // write partials into the dead K tile (row = wave*64 + lane, stride 20)
#pragma unroll
  for (int c4 = 0; c4 < 4; ++c4)
    *(float4*)(&ldsKO[wave * 64 + lane][c4 * 4]) = acc[c4];
  __syncthreads();

  // final reduce + write: thread t -> row t>>2, c4 t&3
  {
    int row = t >> 2, c4 = t & 3;
    float4 a0 = *(const float4*)(&ldsKO[row][c4 * 4]);
    float4 a1 = *(const float4*)(&ldsKO[64 + row][c4 * 4]);
    float4 a2 = *(const float4*)(&ldsKO[128 + row][c4 * 4]);
    float4 a3 = *(const float4*)(&ldsKO[192 + row][c4 * 4]);
    float inv = 1.f / (red_l[0][row] + red_l[1][row] + red_l[2][row] + red_l[3][row]);
    float4 o;
    o.x = (a0.x + a1.x + a2.x + a3.x) * inv;
    o.y = (a0.y + a1.y + a2.y + a3.y) * inv;
    o.z = (a0.z + a1.z + a2.z + a3.z) * inv;
    o.w = (a0.w + a1.w + a2.w + a3.w) * inv;
    size_t dst = (size_t)voxel_row(p, row) * 128 + h * 16 + c4 * 4;
    *(float4*)(ao + dst) = o;
  }
}

// ---------------- output projection, in-place on the `out` region ----------------
__global__ __launch_bounds__(256) void k_proj(
    float* io, const float* __restrict__ w, const float* __restrict__ bias) {
  __shared__ float ldsA[64][132];
  const int p = blockIdx.x, t = threadIdx.x;
#pragma unroll
  for (int i = 0; i < 8; ++i) {
    int idx = t + i * 256;
    int pix = idx >> 5, k4 = idx & 31;
    *(float4*)(&ldsA[pix][k4 * 4]) =
        *(const float4*)(io + (size_t)voxel_row(p, pix) * 128 + k4 * 4);
  }
  __syncthreads();
  const int cg = t & 15, rg = t >> 4;
  const float* wcol = w + cg * 8;
  float4 acc[4][2];
#pragma unroll
  for (int r = 0; r < 4; ++r) {
    acc[r][0] = float4{0.f, 0.f, 0.f, 0.f};
    acc[r][1] = float4{0.f, 0.f, 0.f, 0.f};
  }
  for (int kk = 0; kk < 128; kk += 4) {
    float4 a[4];
#pragma unroll
    for (int r = 0; r < 4; ++r) a[r] = *(const float4*)(&ldsA[rg * 4 + r][kk]);
#pragma unroll
    for (int dk = 0; dk < 4; ++dk) {
      float4 w0 = *(const float4*)(wcol + (kk + dk) * 128);
      float4 w1 = *(const float4*)(wcol + (kk + dk) * 128 + 4);
#pragma unroll
      for (int r = 0; r < 4; ++r) {
        float av = (&a[r].x)[dk];
        fma4(acc[r][0], av, w0);
        fma4(acc[r][1], av, w1);
      }
    }
  }
  float4 b0 = *(const float4*)(bias + cg * 8);
  float4 b1 = *(const float4*)(bias + cg * 8 + 4);
#pragma unroll
  for (int r = 0; r < 4; ++r) {
    float4 o0 = acc[r][0], o1 = acc[r][1];
    o0.x += b0.x; o0.y += b0.y; o0.z += b0.z; o0.w += b0.w;
    o1.x += b1.x; o1.y += b1.y; o1.z += b1.z; o1.w += b1.w;
    size_t row = (size_t)voxel_row(p, rg * 4 + r) * 128 + cg * 8;
    *(float4*)(io + row) = o0;
    *(float4*)(io + row + 4) = o1;
  }
}

}  // namespace

extern "C" void kernel_launch(void* const* d_in, const int* in_sizes, int n_in,
                              void* d_out, int out_size, void* d_ws, size_t ws_size,
                              hipStream_t stream) {
  (void)in_sizes; (void)n_in; (void)out_size; (void)ws_size;
  const float* x = (const float*)d_in[0];
  const float* w_qkv = (const float*)d_in[1];
  const float* b_qkv = (const float*)d_in[2];
  const float* w_o = (const float*)d_in[3];
  const float* b_o = (const float*)d_in[4];

  float* out = (float*)d_out;
  float* q = out + 4194304;
  float* k = q + 4194304;
  float* v = k + 4194304;

  float* qwin = (float*)d_ws;
  float* kwin = qwin + 512 * 128;
  int* ridx = (int*)(kwin + 512 * 128);

  k_qkv<<<dim3(3, 512), 256, 0, stream>>>(x, w_qkv, b_qkv, q, k, v);
  k_means<<<512, 128, 0, stream>>>(q, k, qwin, kwin);
  k_route<<<512, 256, 0, stream>>>(qwin, kwin, ridx);
  k_attn<<<dim3(8, 512), 256, 0, stream>>>(q, k, v, ridx, out);
  k_proj<<<512, 256, 0, stream>>>(out, w_o, b_o);
}

// Round 5
// 166.393 us; speedup vs baseline: 3.0584x; 2.0401x over previous
//
#include <hip/hip_runtime.h>
#include <cmath>

namespace {

typedef __attribute__((ext_vector_type(8))) short short8;
typedef __attribute__((ext_vector_type(4))) float f32x4;

constexpr float kScale = 0.08838834764831845f;  // 128^-0.5

__device__ __forceinline__ int voxel_row(int p, int pix) {
  int pd = p >> 6, ph = (p >> 3) & 7, pw = p & 7;
  int iz = pix >> 4, iy = (pix >> 2) & 3, ix = pix & 3;
  return (((pd * 4 + iz) * 32 + (ph * 4 + iy)) * 32 + (pw * 4 + ix));
}

__device__ __forceinline__ void fma4(float4& a, float s, float4 b) {
  a.x = fmaf(s, b.x, a.x); a.y = fmaf(s, b.y, a.y);
  a.z = fmaf(s, b.z, a.z); a.w = fmaf(s, b.w, a.w);
}

__device__ __forceinline__ float dot4(float4 a, float4 b) {
  return a.x * b.x + a.y * b.y + a.z * b.z + a.w * b.w;
}

__device__ __forceinline__ short bf16c(float f) {
  unsigned u = __builtin_bit_cast(unsigned, f);
  u += 0x7fffu + ((u >> 16) & 1u);
  return (short)(u >> 16);
}

__device__ __forceinline__ unsigned bfpack(float lo, float hi) {
  return (unsigned)(unsigned short)bf16c(lo) |
         ((unsigned)(unsigned short)bf16c(hi) << 16);
}

// ---------------- QKV projection (unchanged) ----------------
__global__ __launch_bounds__(256) void k_qkv(
    const float* __restrict__ x, const float* __restrict__ w,
    const float* __restrict__ bias, float* __restrict__ q,
    float* __restrict__ k, float* __restrict__ v) {
  __shared__ float ldsA[64][132];
  const int ct = blockIdx.x, p = blockIdx.y, t = threadIdx.x;
#pragma unroll
  for (int i = 0; i < 8; ++i) {
    int idx = t + i * 256;
    int pix = idx >> 5, k4 = idx & 31;
    float4 val = *(const float4*)(x + (size_t)voxel_row(p, pix) * 128 + k4 * 4);
    *(float4*)(&ldsA[pix][k4 * 4]) = val;
  }
  __syncthreads();
  const int cg = t & 15, rg = t >> 4;
  const float* wcol = w + ct * 128 + cg * 8;
  float4 acc[4][2];
#pragma unroll
  for (int r = 0; r < 4; ++r) {
    acc[r][0] = float4{0.f, 0.f, 0.f, 0.f};
    acc[r][1] = float4{0.f, 0.f, 0.f, 0.f};
  }
  for (int kk = 0; kk < 128; kk += 4) {
    float4 a[4];
#pragma unroll
    for (int r = 0; r < 4; ++r) a[r] = *(const float4*)(&ldsA[rg * 4 + r][kk]);
#pragma unroll
    for (int dk = 0; dk < 4; ++dk) {
      float4 w0 = *(const float4*)(wcol + (kk + dk) * 384);
      float4 w1 = *(const float4*)(wcol + (kk + dk) * 384 + 4);
#pragma unroll
      for (int r = 0; r < 4; ++r) {
        float av = (&a[r].x)[dk];
        fma4(acc[r][0], av, w0);
        fma4(acc[r][1], av, w1);
      }
    }
  }
  float* dst = (ct == 0) ? q : (ct == 1) ? k : v;
  float4 b0 = *(const float4*)(bias + ct * 128 + cg * 8);
  float4 b1 = *(const float4*)(bias + ct * 128 + cg * 8 + 4);
#pragma unroll
  for (int r = 0; r < 4; ++r) {
    float4 o0 = acc[r][0], o1 = acc[r][1];
    o0.x += b0.x; o0.y += b0.y; o0.z += b0.z; o0.w += b0.w;
    o1.x += b1.x; o1.y += b1.y; o1.z += b1.z; o1.w += b1.w;
    size_t row = (size_t)(p * 64 + rg * 4 + r) * 128 + cg * 8;
    *(float4*)(dst + row) = o0;
    *(float4*)(dst + row + 4) = o1;
  }
}

// ---------------- window means (unchanged) ----------------
__global__ __launch_bounds__(128) void k_means(
    const float* __restrict__ q, const float* __restrict__ k,
    float* __restrict__ qwin, float* __restrict__ kwin) {
  const int p = blockIdx.x, c = threadIdx.x;
  float sq = 0.f, sk = 0.f;
  for (int pix = 0; pix < 64; ++pix) {
    sq += q[((size_t)p * 64 + pix) * 128 + c];
    sk += k[((size_t)p * 64 + pix) * 128 + c];
  }
  qwin[p * 128 + c] = sq * (1.f / 64.f);
  kwin[p * 128 + c] = sk * (1.f / 64.f);
}

// ---------------- routing (unchanged) ----------------
__global__ __launch_bounds__(256) void k_route(
    const float* __restrict__ qwin, const float* __restrict__ kwin,
    int* __restrict__ ridx) {
  __shared__ float qs[128];
  __shared__ float lg[512];
  __shared__ float rv[256];
  __shared__ int ri[256];
  const int p = blockIdx.x, t = threadIdx.x;
  if (t < 32) *(float4*)(&qs[t * 4]) = *(const float4*)(qwin + p * 128 + t * 4);
  __syncthreads();
  for (int jj = t; jj < 512; jj += 256) {
    const float* kr = kwin + (size_t)jj * 128;
    float s = 0.f;
    for (int c = 0; c < 128; c += 4) {
      float4 k4 = *(const float4*)(kr + c);
      float4 q4 = *(const float4*)(qs + c);
      s += dot4(q4, k4);
    }
    lg[jj] = s;
  }
  __syncthreads();
  for (int sel = 0; sel < 4; ++sel) {
    float bv = lg[t];
    int bi = t;
    float v2 = lg[t + 256];
    if (v2 > bv) { bv = v2; bi = t + 256; }
    rv[t] = bv; ri[t] = bi;
    __syncthreads();
    for (int off = 128; off > 0; off >>= 1) {
      if (t < off && rv[t + off] > rv[t]) { rv[t] = rv[t + off]; ri[t] = ri[t + off]; }
      __syncthreads();
    }
    if (t == 0) { ridx[p * 4 + sel] = ri[0]; lg[ri[0]] = -INFINITY; }
    __syncthreads();
  }
}

// ---------------- MFMA attention: one block per window, wave = head --------
// S^T = K*Q^T via mfma_f32_16x16x32_bf16 (16 real dims zero-padded to K=32).
// LDS budget: sK[64][136] (17408 B) unioned with sP[8][64][40] (40960 B),
// plus sV[64][132] (16896 B) => 57872 B static.
__global__ __launch_bounds__(512) void k_attn(
    const float* __restrict__ q, const float* __restrict__ k,
    const float* __restrict__ v, const int* __restrict__ ridx,
    float* __restrict__ ao) {
  __shared__ __align__(16) char smem[40960 + 16896];
  short* sKbase = (short*)smem;                    // sK[row][136]
  short* sPbase = (short*)smem;                    // sP[wave][qrow][40] (alias)
  short* sVbase = (short*)(smem + 40960);          // sV[row][132]
  __shared__ int widx[4];

  const int p = blockIdx.x, t = threadIdx.x;
  const int wave = t >> 6, lane = t & 63;
  const int l15 = lane & 15, lg = lane >> 4;  // lg 0..3
  const int h = wave;
  if (t < 4) widx[t] = ridx[p * 4 + t];

  // Q B-fragments straight from global: B[k=d][col=q], col=l15 -> q row,
  // k = lg*8+i -> dim h*16+lg*8+i (real for lg<2, zero-pad lg>=2)
  short8 qf[4];
#pragma unroll
  for (int nt = 0; nt < 4; ++nt) {
    if (lg < 2) {
      const float* src = q + ((size_t)(p * 64 + nt * 16 + l15)) * 128 + h * 16 + lg * 8;
      float4 a = *(const float4*)src, b = *(const float4*)(src + 4);
      short8 o;
      o[0] = bf16c(a.x); o[1] = bf16c(a.y); o[2] = bf16c(a.z); o[3] = bf16c(a.w);
      o[4] = bf16c(b.x); o[5] = bf16c(b.y); o[6] = bf16c(b.z); o[7] = bf16c(b.w);
      qf[nt] = o;
    } else {
      qf[nt] = short8{0, 0, 0, 0, 0, 0, 0, 0};
    }
  }

  float m_r[4], l_r[4];
  f32x4 oacc[4];
#pragma unroll
  for (int i = 0; i < 4; ++i) {
    m_r[i] = -1e30f;
    l_r[i] = 0.f;
    oacc[i] = f32x4{0.f, 0.f, 0.f, 0.f};
  }

  for (int c = 0; c < 4; ++c) {
    __syncthreads();  // (A) prev-chunk sP/sV reads done; widx visible
    const int wsel = widx[c];
    // stage K chunk: rows 64 x 128 dims bf16, row stride 136 shorts (272 B)
#pragma unroll
    for (int r = 0; r < 2; ++r) {
      int unit = t + r * 512;           // 1024 units of 8 floats
      int row = unit >> 4, u = unit & 15;
      const float* src = k + ((size_t)(wsel * 64 + row)) * 128 + u * 8;
      float4 a = *(const float4*)src, b = *(const float4*)(src + 4);
      short8 o;
      o[0] = bf16c(a.x); o[1] = bf16c(a.y); o[2] = bf16c(a.z); o[3] = bf16c(a.w);
      o[4] = bf16c(b.x); o[5] = bf16c(b.y); o[6] = bf16c(b.z); o[7] = bf16c(b.w);
      *(short8*)(sKbase + row * 136 + u * 8) = o;
    }
    // stage V chunk: row stride 132 shorts (264 B), u32 pair writes
#pragma unroll
    for (int jj = 0; jj < 8; ++jj) {
      int pi = t + jj * 512;            // 4096 pairs
      int row = pi >> 6, d2 = pi & 63;
      const float* src = v + ((size_t)(wsel * 64 + row)) * 128 + d2 * 2;
      *(unsigned*)(sVbase + row * 132 + d2 * 2) = bfpack(src[0], src[1]);
    }
    __syncthreads();  // (B) staging complete

    // A-frags: A[row=key][k=d], row=l15 -> key mt*16+l15, k=lg*8+i
    short8 af[4];
#pragma unroll
    for (int mt = 0; mt < 4; ++mt) {
      if (lg < 2)
        af[mt] = *(const short8*)(sKbase + (mt * 16 + l15) * 136 + h * 16 + lg * 8);
      else
        af[mt] = short8{0, 0, 0, 0, 0, 0, 0, 0};
    }
    f32x4 s[4][4];
#pragma unroll
    for (int mt = 0; mt < 4; ++mt)
#pragma unroll
      for (int nt = 0; nt < 4; ++nt)
        s[mt][nt] = __builtin_amdgcn_mfma_f32_16x16x32_bf16(
            af[mt], qf[nt], f32x4{0.f, 0.f, 0.f, 0.f}, 0, 0, 0);

    // online softmax per q-block nt (C: col=l15=q, row=lg*4+j=key)
    float scale_f[4];
#pragma unroll
    for (int nt = 0; nt < 4; ++nt) {
      float mx = -1e30f;
#pragma unroll
      for (int mt = 0; mt < 4; ++mt)
#pragma unroll
        for (int j = 0; j < 4; ++j) {
          s[mt][nt][j] *= kScale;
          mx = fmaxf(mx, s[mt][nt][j]);
        }
      mx = fmaxf(mx, __shfl_xor(mx, 16));
      mx = fmaxf(mx, __shfl_xor(mx, 32));
      float mnew = fmaxf(m_r[nt], mx);
      scale_f[nt] = __expf(m_r[nt] - mnew);
      m_r[nt] = mnew;
      float ls = 0.f;
#pragma unroll
      for (int mt = 0; mt < 4; ++mt)
#pragma unroll
        for (int j = 0; j < 4; ++j) {
          float e = __expf(s[mt][nt][j] - mnew);
          s[mt][nt][j] = e;
          ls += e;
        }
      ls += __shfl_xor(ls, 16);
      ls += __shfl_xor(ls, 32);
      l_r[nt] = l_r[nt] * scale_f[nt] + ls;
    }

    // rescale O (oacc C: col=l15=dim, row=lg*4+j -> q=mt*16+lg*4+j)
#pragma unroll
    for (int mt = 0; mt < 4; ++mt)
#pragma unroll
      for (int j = 0; j < 4; ++j) {
        float f = __shfl(scale_f[mt], lg * 4 + j);
        oacc[mt][j] *= f;
      }

    __syncthreads();  // (C) all waves done reading sK -> safe to alias as sP

    short* sPw = sPbase + wave * (64 * 40);
#pragma unroll
    for (int kt = 0; kt < 2; ++kt) {
      // write P half (32 keys): frag mtS=kt*2+mm holds keys mtS*16+lg*4+j
#pragma unroll
      for (int mm = 0; mm < 2; ++mm) {
        int mtS = kt * 2 + mm;
        int keyb = mm * 16 + lg * 4;    // local key within 32-key half
#pragma unroll
        for (int nt = 0; nt < 4; ++nt) {
          int qrow = nt * 16 + l15;
          *(unsigned*)(sPw + qrow * 40 + keyb) = bfpack(s[mtS][nt][0], s[mtS][nt][1]);
          *(unsigned*)(sPw + qrow * 40 + keyb + 2) = bfpack(s[mtS][nt][2], s[mtS][nt][3]);
        }
      }
      // A-frag P[q=mtP*16+l15][keys lg*8..+7]
      short8 pf[4];
#pragma unroll
      for (int mtP = 0; mtP < 4; ++mtP)
        pf[mtP] = *(const short8*)(sPw + (mtP * 16 + l15) * 40 + lg * 8);
      // B-frag V[key=kt*32+lg*8+i][dim h*16+l15]
      short8 bf;
#pragma unroll
      for (int i = 0; i < 8; ++i)
        bf[i] = sVbase[(kt * 32 + lg * 8 + i) * 132 + h * 16 + l15];
#pragma unroll
      for (int mtP = 0; mtP < 4; ++mtP)
        oacc[mtP] = __builtin_amdgcn_mfma_f32_16x16x32_bf16(pf[mtP], bf, oacc[mtP], 0, 0, 0);
    }
  }

  // epilogue: q = mt*16 + lg*4 + j, dim = h*16 + l15
#pragma unroll
  for (int mt = 0; mt < 4; ++mt)
#pragma unroll
    for (int j = 0; j < 4; ++j) {
      float li = __shfl(l_r[mt], lg * 4 + j);
      int qrow = mt * 16 + lg * 4 + j;
      ao[(size_t)voxel_row(p, qrow) * 128 + h * 16 + l15] = oacc[mt][j] / li;
    }
}

// ---------------- output projection (unchanged) ----------------
__global__ __launch_bounds__(256) void k_proj(
    float* io, const float* __restrict__ w, const float* __restrict__ bias) {
  __shared__ float ldsA[64][132];
  const int p = blockIdx.x, t = threadIdx.x;
#pragma unroll
  for (int i = 0; i < 8; ++i) {
    int idx = t + i * 256;
    int pix = idx >> 5, k4 = idx & 31;
    *(float4*)(&ldsA[pix][k4 * 4]) =
        *(const float4*)(io + (size_t)voxel_row(p, pix) * 128 + k4 * 4);
  }
  __syncthreads();
  const int cg = t & 15, rg = t >> 4;
  const float* wcol = w + cg * 8;
  float4 acc[4][2];
#pragma unroll
  for (int r = 0; r < 4; ++r) {
    acc[r][0] = float4{0.f, 0.f, 0.f, 0.f};
    acc[r][1] = float4{0.f, 0.f, 0.f, 0.f};
  }
  for (int kk = 0; kk < 128; kk += 4) {
    float4 a[4];
#pragma unroll
    for (int r = 0; r < 4; ++r) a[r] = *(const float4*)(&ldsA[rg * 4 + r][kk]);
#pragma unroll
    for (int dk = 0; dk < 4; ++dk) {
      float4 w0 = *(const float4*)(wcol + (kk + dk) * 128);
      float4 w1 = *(const float4*)(wcol + (kk + dk) * 128 + 4);
#pragma unroll
      for (int r = 0; r < 4; ++r) {
        float av = (&a[r].x)[dk];
        fma4(acc[r][0], av, w0);
        fma4(acc[r][1], av, w1);
      }
    }
  }
  float4 b0 = *(const float4*)(bias + cg * 8);
  float4 b1 = *(const float4*)(bias + cg * 8 + 4);
#pragma unroll
  for (int r = 0; r < 4; ++r) {
    float4 o0 = acc[r][0], o1 = acc[r][1];
    o0.x += b0.x; o0.y += b0.y; o0.z += b0.z; o0.w += b0.w;
    o1.x += b1.x; o1.y += b1.y; o1.z += b1.z; o1.w += b1.w;
    size_t row = (size_t)voxel_row(p, rg * 4 + r) * 128 + cg * 8;
    *(float4*)(io + row) = o0;
    *(float4*)(io + row + 4) = o1;
  }
}

}  // namespace

extern "C" void kernel_launch(void* const* d_in, const int* in_sizes, int n_in,
                              void* d_out, int out_size, void* d_ws, size_t ws_size,
                              hipStream_t stream) {
  (void)in_sizes; (void)n_in; (void)out_size; (void)ws_size;
  const float* x = (const float*)d_in[0];
  const float* w_qkv = (const float*)d_in[1];
  const float* b_qkv = (const float*)d_in[2];
  const float* w_o = (const float*)d_in[3];
  const float* b_o = (const float*)d_in[4];

  float* out = (float*)d_out;
  float* q = out + 4194304;
  float* k = q + 4194304;
  float* v = k + 4194304;

  float* qwin = (float*)d_ws;
  float* kwin = qwin + 512 * 128;
  int* ridx = (int*)(kwin + 512 * 128);

  k_qkv<<<dim3(3, 512), 256, 0, stream>>>(x, w_qkv, b_qkv, q, k, v);
  k_means<<<512, 128, 0, stream>>>(q, k, qwin, kwin);
  k_route<<<512, 256, 0, stream>>>(qwin, kwin, ridx);
  k_attn<<<512, 512, 0, stream>>>(q, k, v, ridx, out);
  k_proj<<<512, 256, 0, stream>>>(out, w_o, b_o);
}

// Round 6
// 108.471 us; speedup vs baseline: 4.6915x; 1.5340x over previous
//
#include <hip/hip_runtime.h>
#include <cmath>

namespace {

typedef __attribute__((ext_vector_type(8))) short short8;
typedef __attribute__((ext_vector_type(4))) float f32x4;

constexpr float kScale = 0.08838834764831845f;  // 128^-0.5

__device__ __forceinline__ int voxel_row(int p, int pix) {
  int pd = p >> 6, ph = (p >> 3) & 7, pw = p & 7;
  int iz = pix >> 4, iy = (pix >> 2) & 3, ix = pix & 3;
  return (((pd * 4 + iz) * 32 + (ph * 4 + iy)) * 32 + (pw * 4 + ix));
}

__device__ __forceinline__ float dot4(float4 a, float4 b) {
  return a.x * b.x + a.y * b.y + a.z * b.z + a.w * b.w;
}

__device__ __forceinline__ short bf16c(float f) {
  unsigned u = __builtin_bit_cast(unsigned, f);
  u += 0x7fffu + ((u >> 16) & 1u);
  return (short)(u >> 16);
}

__device__ __forceinline__ unsigned bfpack(float lo, float hi) {
  return (unsigned)(unsigned short)bf16c(lo) |
         ((unsigned)(unsigned short)bf16c(hi) << 16);
}

__device__ __forceinline__ short8 cvt8(const float* src) {
  float4 a = *(const float4*)src, b = *(const float4*)(src + 4);
  short8 o;
  o[0] = bf16c(a.x); o[1] = bf16c(a.y); o[2] = bf16c(a.z); o[3] = bf16c(a.w);
  o[4] = bf16c(b.x); o[5] = bf16c(b.y); o[6] = bf16c(b.z); o[7] = bf16c(b.w);
  return o;
}

// ---- pack weight (K=128 x N) into per-lane MFMA B-fragments ----
// dst frag f = blockIdx.x = ntile*4 + ks; element: lane, i ->
// B[k = ks*32 + (lane>>4)*8 + i][col = ntile*16 + (lane&15)]
__global__ __launch_bounds__(64) void k_pack(
    const float* __restrict__ w, short* __restrict__ dst, int N) {
  const int lane = threadIdx.x;
  const int ntile = blockIdx.x >> 2, ks = blockIdx.x & 3;
  const int k0 = ks * 32 + (lane >> 4) * 8, col = ntile * 16 + (lane & 15);
  short8 o;
#pragma unroll
  for (int i = 0; i < 8; ++i) o[i] = bf16c(w[(size_t)(k0 + i) * N + col]);
  *(short8*)(dst + ((size_t)blockIdx.x * 64 + lane) * 8) = o;
}

// ---- window means via mean/linear commutation: win = mean(x) @ W + b ----
// exact-f32 path so routing logits match the reference bit-closely.
__global__ __launch_bounds__(256) void k_winmean(
    const float* __restrict__ x, const float* __restrict__ w,
    const float* __restrict__ bias, float* __restrict__ qwin,
    float* __restrict__ kwin) {
  __shared__ float xm[128];
  const int p = blockIdx.x, t = threadIdx.x;
  if (t < 128) {
    float s = 0.f;
    for (int pix = 0; pix < 64; ++pix)
      s += x[(size_t)voxel_row(p, pix) * 128 + t];
    xm[t] = s * (1.f / 64.f);
  }
  __syncthreads();
  float s = bias[t];  // t in [0,256): q cols then k cols
  for (int kk = 0; kk < 128; ++kk)
    s = fmaf(xm[kk], w[(size_t)kk * 384 + t], s);
  if (t < 128) qwin[p * 128 + t] = s;
  else kwin[p * 128 + (t - 128)] = s;
}

// ---- QKV projection, MFMA: per window 64x128 @ 128x384 ----
__global__ __launch_bounds__(256) void k_qkv(
    const float* __restrict__ x, const short* __restrict__ wpk,
    const float* __restrict__ bias, float* __restrict__ q,
    float* __restrict__ k, float* __restrict__ v) {
  __shared__ short sX[64][136];
  const int p = blockIdx.x, t = threadIdx.x;
  const int wave = t >> 6, lane = t & 63, l15 = lane & 15, lg = lane >> 4;
#pragma unroll
  for (int r = 0; r < 4; ++r) {
    int unit = t + r * 256;  // 1024 units of 8 floats
    int row = unit >> 4, u = unit & 15;
    *(short8*)(&sX[row][u * 8]) =
        cvt8(x + (size_t)voxel_row(p, row) * 128 + u * 8);
  }
  __syncthreads();
  f32x4 acc[4][6];
#pragma unroll
  for (int mt = 0; mt < 4; ++mt)
#pragma unroll
    for (int nt = 0; nt < 6; ++nt) acc[mt][nt] = f32x4{0.f, 0.f, 0.f, 0.f};
#pragma unroll
  for (int ks = 0; ks < 4; ++ks) {
    short8 a[4];
#pragma unroll
    for (int mt = 0; mt < 4; ++mt)
      a[mt] = *(const short8*)(&sX[mt * 16 + l15][ks * 32 + lg * 8]);
#pragma unroll
    for (int nt = 0; nt < 6; ++nt) {
      int ntg = wave * 6 + nt;
      short8 b = *(const short8*)(wpk + ((size_t)(ntg * 4 + ks) * 64 + lane) * 8);
#pragma unroll
      for (int mt = 0; mt < 4; ++mt)
        acc[mt][nt] = __builtin_amdgcn_mfma_f32_16x16x32_bf16(a[mt], b, acc[mt][nt], 0, 0, 0);
    }
  }
  // epilogue: C col=l15, row=lg*4+j
#pragma unroll
  for (int nt = 0; nt < 6; ++nt) {
    int n = (wave * 6 + nt) * 16 + l15;
    float bv = bias[n];
    float* dst = n < 128 ? q : (n < 256 ? k : v);
    int col = n & 127;
#pragma unroll
    for (int mt = 0; mt < 4; ++mt)
#pragma unroll
      for (int j = 0; j < 4; ++j)
        dst[(size_t)(p * 64 + mt * 16 + lg * 4 + j) * 128 + col] = acc[mt][nt][j] + bv;
  }
}

// ---------------- routing (unchanged) ----------------
__global__ __launch_bounds__(256) void k_route(
    const float* __restrict__ qwin, const float* __restrict__ kwin,
    int* __restrict__ ridx) {
  __shared__ float qs[128];
  __shared__ float lg[512];
  __shared__ float rv[256];
  __shared__ int ri[256];
  const int p = blockIdx.x, t = threadIdx.x;
  if (t < 32) *(float4*)(&qs[t * 4]) = *(const float4*)(qwin + p * 128 + t * 4);
  __syncthreads();
  for (int jj = t; jj < 512; jj += 256) {
    const float* kr = kwin + (size_t)jj * 128;
    float s = 0.f;
    for (int c = 0; c < 128; c += 4) {
      float4 k4 = *(const float4*)(kr + c);
      float4 q4 = *(const float4*)(qs + c);
      s += dot4(q4, k4);
    }
    lg[jj] = s;
  }
  __syncthreads();
  for (int sel = 0; sel < 4; ++sel) {
    float bv = lg[t];
    int bi = t;
    float v2 = lg[t + 256];
    if (v2 > bv) { bv = v2; bi = t + 256; }
    rv[t] = bv; ri[t] = bi;
    __syncthreads();
    for (int off = 128; off > 0; off >>= 1) {
      if (t < off && rv[t + off] > rv[t]) { rv[t] = rv[t + off]; ri[t] = ri[t + off]; }
      __syncthreads();
    }
    if (t == 0) { ridx[p * 4 + sel] = ri[0]; lg[ri[0]] = -INFINITY; }
    __syncthreads();
  }
}

// ---------------- MFMA attention (unchanged from R5) ----------------
__global__ __launch_bounds__(512) void k_attn(
    const float* __restrict__ q, const float* __restrict__ k,
    const float* __restrict__ v, const int* __restrict__ ridx,
    float* __restrict__ ao) {
  __shared__ __align__(16) char smem[40960 + 16896];
  short* sKbase = (short*)smem;                    // sK[row][136]
  short* sPbase = (short*)smem;                    // sP[wave][qrow][40] (alias)
  short* sVbase = (short*)(smem + 40960);          // sV[row][132]
  __shared__ int widx[4];

  const int p = blockIdx.x, t = threadIdx.x;
  const int wave = t >> 6, lane = t & 63;
  const int l15 = lane & 15, lg = lane >> 4;
  const int h = wave;
  if (t < 4) widx[t] = ridx[p * 4 + t];

  short8 qf[4];
#pragma unroll
  for (int nt = 0; nt < 4; ++nt) {
    if (lg < 2) {
      qf[nt] = cvt8(q + ((size_t)(p * 64 + nt * 16 + l15)) * 128 + h * 16 + lg * 8);
    } else {
      qf[nt] = short8{0, 0, 0, 0, 0, 0, 0, 0};
    }
  }

  float m_r[4], l_r[4];
  f32x4 oacc[4];
#pragma unroll
  for (int i = 0; i < 4; ++i) {
    m_r[i] = -1e30f;
    l_r[i] = 0.f;
    oacc[i] = f32x4{0.f, 0.f, 0.f, 0.f};
  }

  for (int c = 0; c < 4; ++c) {
    __syncthreads();  // (A) prev-chunk sP/sV reads done; widx visible
    const int wsel = widx[c];
#pragma unroll
    for (int r = 0; r < 2; ++r) {
      int unit = t + r * 512;
      int row = unit >> 4, u = unit & 15;
      *(short8*)(sKbase + row * 136 + u * 8) =
          cvt8(k + ((size_t)(wsel * 64 + row)) * 128 + u * 8);
    }
#pragma unroll
    for (int jj = 0; jj < 8; ++jj) {
      int pi = t + jj * 512;
      int row = pi >> 6, d2 = pi & 63;
      const float* src = v + ((size_t)(wsel * 64 + row)) * 128 + d2 * 2;
      *(unsigned*)(sVbase + row * 132 + d2 * 2) = bfpack(src[0], src[1]);
    }
    __syncthreads();  // (B) staging complete

    short8 af[4];
#pragma unroll
    for (int mt = 0; mt < 4; ++mt) {
      if (lg < 2)
        af[mt] = *(const short8*)(sKbase + (mt * 16 + l15) * 136 + h * 16 + lg * 8);
      else
        af[mt] = short8{0, 0, 0, 0, 0, 0, 0, 0};
    }
    f32x4 s[4][4];
#pragma unroll
    for (int mt = 0; mt < 4; ++mt)
#pragma unroll
      for (int nt = 0; nt < 4; ++nt)
        s[mt][nt] = __builtin_amdgcn_mfma_f32_16x16x32_bf16(
            af[mt], qf[nt], f32x4{0.f, 0.f, 0.f, 0.f}, 0, 0, 0);

    float scale_f[4];
#pragma unroll
    for (int nt = 0; nt < 4; ++nt) {
      float mx = -1e30f;
#pragma unroll
      for (int mt = 0; mt < 4; ++mt)
#pragma unroll
        for (int j = 0; j < 4; ++j) {
          s[mt][nt][j] *= kScale;
          mx = fmaxf(mx, s[mt][nt][j]);
        }
      mx = fmaxf(mx, __shfl_xor(mx, 16));
      mx = fmaxf(mx, __shfl_xor(mx, 32));
      float mnew = fmaxf(m_r[nt], mx);
      scale_f[nt] = __expf(m_r[nt] - mnew);
      m_r[nt] = mnew;
      float ls = 0.f;
#pragma unroll
      for (int mt = 0; mt < 4; ++mt)
#pragma unroll
        for (int j = 0; j < 4; ++j) {
          float e = __expf(s[mt][nt][j] - mnew);
          s[mt][nt][j] = e;
          ls += e;
        }
      ls += __shfl_xor(ls, 16);
      ls += __shfl_xor(ls, 32);
      l_r[nt] = l_r[nt] * scale_f[nt] + ls;
    }

#pragma unroll
    for (int mt = 0; mt < 4; ++mt)
#pragma unroll
      for (int j = 0; j < 4; ++j) {
        float f = __shfl(scale_f[mt], lg * 4 + j);
        oacc[mt][j] *= f;
      }

    __syncthreads();  // (C) all waves done reading sK -> safe to alias as sP

    short* sPw = sPbase + wave * (64 * 40);
#pragma unroll
    for (int kt = 0; kt < 2; ++kt) {
#pragma unroll
      for (int mm = 0; mm < 2; ++mm) {
        int mtS = kt * 2 + mm;
        int keyb = mm * 16 + lg * 4;
#pragma unroll
        for (int nt = 0; nt < 4; ++nt) {
          int qrow = nt * 16 + l15;
          *(unsigned*)(sPw + qrow * 40 + keyb) = bfpack(s[mtS][nt][0], s[mtS][nt][1]);
          *(unsigned*)(sPw + qrow * 40 + keyb + 2) = bfpack(s[mtS][nt][2], s[mtS][nt][3]);
        }
      }
      short8 pf[4];
#pragma unroll
      for (int mtP = 0; mtP < 4; ++mtP)
        pf[mtP] = *(const short8*)(sPw + (mtP * 16 + l15) * 40 + lg * 8);
      short8 bf;
#pragma unroll
      for (int i = 0; i < 8; ++i)
        bf[i] = sVbase[(kt * 32 + lg * 8 + i) * 132 + h * 16 + l15];
#pragma unroll
      for (int mtP = 0; mtP < 4; ++mtP)
        oacc[mtP] = __builtin_amdgcn_mfma_f32_16x16x32_bf16(pf[mtP], bf, oacc[mtP], 0, 0, 0);
    }
  }

#pragma unroll
  for (int mt = 0; mt < 4; ++mt)
#pragma unroll
    for (int j = 0; j < 4; ++j) {
      float li = __shfl(l_r[mt], lg * 4 + j);
      int qrow = mt * 16 + lg * 4 + j;
      ao[(size_t)voxel_row(p, qrow) * 128 + h * 16 + l15] = oacc[mt][j] / li;
    }
}

// ---- output projection, MFMA, in-place: per window 64x128 @ 128x128 ----
__global__ __launch_bounds__(256) void k_proj(
    float* io, const short* __restrict__ wpk, const float* __restrict__ bias) {
  __shared__ short sX[64][136];
  const int p = blockIdx.x, t = threadIdx.x;
  const int wave = t >> 6, lane = t & 63, l15 = lane & 15, lg = lane >> 4;
#pragma unroll
  for (int r = 0; r < 4; ++r) {
    int unit = t + r * 256;
    int row = unit >> 4, u = unit & 15;
    *(short8*)(&sX[row][u * 8]) =
        cvt8(io + (size_t)voxel_row(p, row) * 128 + u * 8);
  }
  __syncthreads();
  f32x4 acc[4][2];
#pragma unroll
  for (int mt = 0; mt < 4; ++mt) {
    acc[mt][0] = f32x4{0.f, 0.f, 0.f, 0.f};
    acc[mt][1] = f32x4{0.f, 0.f, 0.f, 0.f};
  }
#pragma unroll
  for (int ks = 0; ks < 4; ++ks) {
    short8 a[4];
#pragma unroll
    for (int mt = 0; mt < 4; ++mt)
      a[mt] = *(const short8*)(&sX[mt * 16 + l15][ks * 32 + lg * 8]);
#pragma unroll
    for (int nt = 0; nt < 2; ++nt) {
      int ntg = wave * 2 + nt;
      short8 b = *(const short8*)(wpk + ((size_t)(ntg * 4 + ks) * 64 + lane) * 8);
#pragma unroll
      for (int mt = 0; mt < 4; ++mt)
        acc[mt][nt] = __builtin_amdgcn_mfma_f32_16x16x32_bf16(a[mt], b, acc[mt][nt], 0, 0, 0);
    }
  }
#pragma unroll
  for (int nt = 0; nt < 2; ++nt) {
    int n = (wave * 2 + nt) * 16 + l15;
    float bv = bias[n];
#pragma unroll
    for (int mt = 0; mt < 4; ++mt)
#pragma unroll
      for (int j = 0; j < 4; ++j)
        io[(size_t)voxel_row(p, mt * 16 + lg * 4 + j) * 128 + n] = acc[mt][nt][j] + bv;
  }
}

}  // namespace

extern "C" void kernel_launch(void* const* d_in, const int* in_sizes, int n_in,
                              void* d_out, int out_size, void* d_ws, size_t ws_size,
                              hipStream_t stream) {
  (void)in_sizes; (void)n_in; (void)out_size; (void)ws_size;
  const float* x = (const float*)d_in[0];
  const float* w_qkv = (const float*)d_in[1];
  const float* b_qkv = (const float*)d_in[2];
  const float* w_o = (const float*)d_in[3];
  const float* b_o = (const float*)d_in[4];

  float* out = (float*)d_out;
  float* q = out + 4194304;
  float* k = q + 4194304;
  float* v = k + 4194304;

  float* qwin = (float*)d_ws;                 // 512*128 f32
  float* kwin = qwin + 512 * 128;             // 512*128 f32
  int* ridx = (int*)(kwin + 512 * 128);       // 512*4 i32
  short* wpk_qkv = (short*)(ridx + 512 * 4);  // 24*4*64*8 shorts (96 KB)
  short* wpk_o = wpk_qkv + 24 * 4 * 64 * 8;   // 8*4*64*8 shorts (32 KB)

  k_pack<<<96, 64, 0, stream>>>(w_qkv, wpk_qkv, 384);
  k_pack<<<32, 64, 0, stream>>>(w_o, wpk_o, 128);
  k_winmean<<<512, 256, 0, stream>>>(x, w_qkv, b_qkv, qwin, kwin);
  k_qkv<<<512, 256, 0, stream>>>(x, wpk_qkv, b_qkv, q, k, v);
  k_route<<<512, 256, 0, stream>>>(qwin, kwin, ridx);
  k_attn<<<512, 512, 0, stream>>>(q, k, v, ridx, out);
  k_proj<<<512, 256, 0, stream>>>(out, wpk_o, b_o);
}

// Round 7
// 101.402 us; speedup vs baseline: 5.0185x; 1.0697x over previous
//
#include <hip/hip_runtime.h>
#include <cmath>

namespace {

typedef __attribute__((ext_vector_type(8))) short short8;
typedef __attribute__((ext_vector_type(4))) float f32x4;

constexpr float kScale = 0.08838834764831845f;  // 128^-0.5

__device__ __forceinline__ int voxel_row(int p, int pix) {
  int pd = p >> 6, ph = (p >> 3) & 7, pw = p & 7;
  int iz = pix >> 4, iy = (pix >> 2) & 3, ix = pix & 3;
  return (((pd * 4 + iz) * 32 + (ph * 4 + iy)) * 32 + (pw * 4 + ix));
}

__device__ __forceinline__ float dot4(float4 a, float4 b) {
  return a.x * b.x + a.y * b.y + a.z * b.z + a.w * b.w;
}

__device__ __forceinline__ short bf16c(float f) {
  unsigned u = __builtin_bit_cast(unsigned, f);
  u += 0x7fffu + ((u >> 16) & 1u);
  return (short)(u >> 16);
}

__device__ __forceinline__ unsigned bfpack(float lo, float hi) {
  return (unsigned)(unsigned short)bf16c(lo) |
         ((unsigned)(unsigned short)bf16c(hi) << 16);
}

__device__ __forceinline__ short8 cvt8(const float* src) {
  float4 a = *(const float4*)src, b = *(const float4*)(src + 4);
  short8 o;
  o[0] = bf16c(a.x); o[1] = bf16c(a.y); o[2] = bf16c(a.z); o[3] = bf16c(a.w);
  o[4] = bf16c(b.x); o[5] = bf16c(b.y); o[6] = bf16c(b.z); o[7] = bf16c(b.w);
  return o;
}

__device__ __forceinline__ short8 cvt8s(const float* src, float sc) {
  float4 a = *(const float4*)src, b = *(const float4*)(src + 4);
  short8 o;
  o[0] = bf16c(a.x * sc); o[1] = bf16c(a.y * sc);
  o[2] = bf16c(a.z * sc); o[3] = bf16c(a.w * sc);
  o[4] = bf16c(b.x * sc); o[5] = bf16c(b.y * sc);
  o[6] = bf16c(b.z * sc); o[7] = bf16c(b.w * sc);
  return o;
}

// ---- pack weight (K=128 x N) into per-lane MFMA B-fragments ----
__global__ __launch_bounds__(64) void k_pack(
    const float* __restrict__ w, short* __restrict__ dst, int N) {
  const int lane = threadIdx.x;
  const int ntile = blockIdx.x >> 2, ks = blockIdx.x & 3;
  const int k0 = ks * 32 + (lane >> 4) * 8, col = ntile * 16 + (lane & 15);
  short8 o;
#pragma unroll
  for (int i = 0; i < 8; ++i) o[i] = bf16c(w[(size_t)(k0 + i) * N + col]);
  *(short8*)(dst + ((size_t)blockIdx.x * 64 + lane) * 8) = o;
}

// ---- window means via mean/linear commutation (exact f32 for routing) ----
__global__ __launch_bounds__(256) void k_winmean(
    const float* __restrict__ x, const float* __restrict__ w,
    const float* __restrict__ bias, float* __restrict__ qwin,
    float* __restrict__ kwin) {
  __shared__ float xm[128];
  const int p = blockIdx.x, t = threadIdx.x;
  if (t < 128) {
    float s = 0.f;
    for (int pix = 0; pix < 64; ++pix)
      s += x[(size_t)voxel_row(p, pix) * 128 + t];
    xm[t] = s * (1.f / 64.f);
  }
  __syncthreads();
  float s = bias[t];
  for (int kk = 0; kk < 128; ++kk)
    s = fmaf(xm[kk], w[(size_t)kk * 384 + t], s);
  if (t < 128) qwin[p * 128 + t] = s;
  else kwin[p * 128 + (t - 128)] = s;
}

// ---- QKV projection, MFMA; also emits V^T bf16 (vt[p][dim][key]) ----
__global__ __launch_bounds__(256) void k_qkv(
    const float* __restrict__ x, const short* __restrict__ wpk,
    const float* __restrict__ bias, float* __restrict__ q,
    float* __restrict__ k, float* __restrict__ v, short* __restrict__ vt) {
  __shared__ short sX[64][136];
  const int p = blockIdx.x, t = threadIdx.x;
  const int wave = t >> 6, lane = t & 63, l15 = lane & 15, lg = lane >> 4;
#pragma unroll
  for (int r = 0; r < 4; ++r) {
    int unit = t + r * 256;
    int row = unit >> 4, u = unit & 15;
    *(short8*)(&sX[row][u * 8]) =
        cvt8(x + (size_t)voxel_row(p, row) * 128 + u * 8);
  }
  __syncthreads();
  f32x4 acc[4][6];
#pragma unroll
  for (int mt = 0; mt < 4; ++mt)
#pragma unroll
    for (int nt = 0; nt < 6; ++nt) acc[mt][nt] = f32x4{0.f, 0.f, 0.f, 0.f};
#pragma unroll
  for (int ks = 0; ks < 4; ++ks) {
    short8 a[4];
#pragma unroll
    for (int mt = 0; mt < 4; ++mt)
      a[mt] = *(const short8*)(&sX[mt * 16 + l15][ks * 32 + lg * 8]);
#pragma unroll
    for (int nt = 0; nt < 6; ++nt) {
      int ntg = wave * 6 + nt;
      short8 b = *(const short8*)(wpk + ((size_t)(ntg * 4 + ks) * 64 + lane) * 8);
#pragma unroll
      for (int mt = 0; mt < 4; ++mt)
        acc[mt][nt] = __builtin_amdgcn_mfma_f32_16x16x32_bf16(a[mt], b, acc[mt][nt], 0, 0, 0);
    }
  }
#pragma unroll
  for (int nt = 0; nt < 6; ++nt) {
    int n = (wave * 6 + nt) * 16 + l15;
    float bv = bias[n];
    float* dst = n < 128 ? q : (n < 256 ? k : v);
    int col = n & 127;
#pragma unroll
    for (int mt = 0; mt < 4; ++mt) {
      float o0 = acc[mt][nt][0] + bv, o1 = acc[mt][nt][1] + bv;
      float o2 = acc[mt][nt][2] + bv, o3 = acc[mt][nt][3] + bv;
      int row0 = mt * 16 + lg * 4;
      dst[(size_t)(p * 64 + row0 + 0) * 128 + col] = o0;
      dst[(size_t)(p * 64 + row0 + 1) * 128 + col] = o1;
      dst[(size_t)(p * 64 + row0 + 2) * 128 + col] = o2;
      dst[(size_t)(p * 64 + row0 + 3) * 128 + col] = o3;
      if (n >= 256) {
        uint2 pk;
        pk.x = bfpack(o0, o1);
        pk.y = bfpack(o2, o3);
        *(uint2*)(vt + (size_t)p * 8192 + (size_t)(n - 256) * 64 + row0) = pk;
      }
    }
  }
}

// ---------------- routing (unchanged) ----------------
__global__ __launch_bounds__(256) void k_route(
    const float* __restrict__ qwin, const float* __restrict__ kwin,
    int* __restrict__ ridx) {
  __shared__ float qs[128];
  __shared__ float lg[512];
  __shared__ float rv[256];
  __shared__ int ri[256];
  const int p = blockIdx.x, t = threadIdx.x;
  if (t < 32) *(float4*)(&qs[t * 4]) = *(const float4*)(qwin + p * 128 + t * 4);
  __syncthreads();
  for (int jj = t; jj < 512; jj += 256) {
    const float* kr = kwin + (size_t)jj * 128;
    float s = 0.f;
    for (int c = 0; c < 128; c += 4) {
      float4 k4 = *(const float4*)(kr + c);
      float4 q4 = *(const float4*)(qs + c);
      s += dot4(q4, k4);
    }
    lg[jj] = s;
  }
  __syncthreads();
  for (int sel = 0; sel < 4; ++sel) {
    float bv = lg[t];
    int bi = t;
    float v2 = lg[t + 256];
    if (v2 > bv) { bv = v2; bi = t + 256; }
    rv[t] = bv; ri[t] = bi;
    __syncthreads();
    for (int off = 128; off > 0; off >>= 1) {
      if (t < off && rv[t + off] > rv[t]) { rv[t] = rv[t + off]; ri[t] = ri[t + off]; }
      __syncthreads();
    }
    if (t == 0) { ridx[p * 4 + sel] = ri[0]; lg[ri[0]] = -INFINITY; }
    __syncthreads();
  }
}

// ---- MFMA attention, barrier-free: grid (1024), 4 waves, wave = head ----
// Q/K fragments direct from global f32 (+cvt); V B-frags direct from vt bf16;
// only per-wave sP LDS (P round-trip). No __syncthreads anywhere.
__global__ __launch_bounds__(256) void k_attn(
    const float* __restrict__ q, const float* __restrict__ k,
    const short* __restrict__ vt, const int* __restrict__ ridx,
    float* __restrict__ ao) {
  __shared__ short sP[4][64][72];
  const int p = blockIdx.x >> 1, t = threadIdx.x;
  const int wave = t >> 6, lane = t & 63;
  const int l15 = lane & 15, lg = lane >> 4;
  const int h = ((blockIdx.x & 1) << 2) + wave;

  // Q B-fragments, pre-scaled by kScale
  short8 qf[4];
#pragma unroll
  for (int nt = 0; nt < 4; ++nt) {
    if (lg < 2)
      qf[nt] = cvt8s(q + ((size_t)(p * 64 + nt * 16 + l15)) * 128 + h * 16 + lg * 8, kScale);
    else
      qf[nt] = short8{0, 0, 0, 0, 0, 0, 0, 0};
  }

  float m_r[4], l_r[4];
  f32x4 oacc[4];
#pragma unroll
  for (int i = 0; i < 4; ++i) {
    m_r[i] = -1e30f;
    l_r[i] = 0.f;
    oacc[i] = f32x4{0.f, 0.f, 0.f, 0.f};
  }

  short* sPw = &sP[wave][0][0];
  for (int c = 0; c < 4; ++c) {
    const int wsel = ridx[p * 4 + c];
    // K A-fragments direct from global
    short8 af[4];
#pragma unroll
    for (int mt = 0; mt < 4; ++mt) {
      if (lg < 2)
        af[mt] = cvt8(k + ((size_t)(wsel * 64 + mt * 16 + l15)) * 128 + h * 16 + lg * 8);
      else
        af[mt] = short8{0, 0, 0, 0, 0, 0, 0, 0};
    }
    float sc[4];
#pragma unroll
    for (int nt = 0; nt < 4; ++nt) {
      f32x4 s[4];
#pragma unroll
      for (int mt = 0; mt < 4; ++mt)
        s[mt] = __builtin_amdgcn_mfma_f32_16x16x32_bf16(
            af[mt], qf[nt], f32x4{0.f, 0.f, 0.f, 0.f}, 0, 0, 0);
      // online softmax for q-block nt (col=l15 is q, row lg*4+j is key)
      float mx = -1e30f;
#pragma unroll
      for (int mt = 0; mt < 4; ++mt)
#pragma unroll
        for (int j = 0; j < 4; ++j) mx = fmaxf(mx, s[mt][j]);
      mx = fmaxf(mx, __shfl_xor(mx, 16));
      mx = fmaxf(mx, __shfl_xor(mx, 32));
      float mnew = fmaxf(m_r[nt], mx);
      sc[nt] = __expf(m_r[nt] - mnew);
      m_r[nt] = mnew;
      float ls = 0.f;
#pragma unroll
      for (int mt = 0; mt < 4; ++mt)
#pragma unroll
        for (int j = 0; j < 4; ++j) {
          float e = __expf(s[mt][j] - mnew);
          s[mt][j] = e;
          ls += e;
        }
      ls += __shfl_xor(ls, 16);
      ls += __shfl_xor(ls, 32);
      l_r[nt] = l_r[nt] * sc[nt] + ls;
      // P rows q=nt*16+l15, keys mt*16+lg*4..+3 (bf16)
      int qoff = (nt * 16 + l15) * 72;
#pragma unroll
      for (int mt = 0; mt < 4; ++mt) {
        *(unsigned*)(sPw + qoff + mt * 16 + lg * 4) = bfpack(s[mt][0], s[mt][1]);
        *(unsigned*)(sPw + qoff + mt * 16 + lg * 4 + 2) = bfpack(s[mt][2], s[mt][3]);
      }
    }
    // rescale O accumulators (q-row = nt*16 + lg*4 + j)
#pragma unroll
    for (int nt = 0; nt < 4; ++nt)
#pragma unroll
      for (int j = 0; j < 4; ++j) {
        float f = __shfl(sc[nt], lg * 4 + j);
        oacc[nt][j] *= f;
      }
    // PV: A = P (from sP), B = V column-slice (contiguous in vt)
    const short* vw = vt + (size_t)wsel * 8192 + (size_t)(h * 16 + l15) * 64;
#pragma unroll
    for (int kt = 0; kt < 2; ++kt) {
      short8 bf = *(const short8*)(vw + kt * 32 + lg * 8);
#pragma unroll
      for (int mtP = 0; mtP < 4; ++mtP) {
        short8 pf = *(const short8*)(sPw + (mtP * 16 + l15) * 72 + kt * 32 + lg * 8);
        oacc[mtP] = __builtin_amdgcn_mfma_f32_16x16x32_bf16(pf, bf, oacc[mtP], 0, 0, 0);
      }
    }
  }

  // epilogue: q = mt*16 + lg*4 + j, dim = h*16 + l15
#pragma unroll
  for (int mt = 0; mt < 4; ++mt)
#pragma unroll
    for (int j = 0; j < 4; ++j) {
      float li = __shfl(l_r[mt], lg * 4 + j);
      int qrow = mt * 16 + lg * 4 + j;
      ao[(size_t)voxel_row(p, qrow) * 128 + h * 16 + l15] = oacc[mt][j] / li;
    }
}

// ---- output projection, MFMA, in-place (unchanged from R6) ----
__global__ __launch_bounds__(256) void k_proj(
    float* io, const short* __restrict__ wpk, const float* __restrict__ bias) {
  __shared__ short sX[64][136];
  const int p = blockIdx.x, t = threadIdx.x;
  const int wave = t >> 6, lane = t & 63, l15 = lane & 15, lg = lane >> 4;
#pragma unroll
  for (int r = 0; r < 4; ++r) {
    int unit = t + r * 256;
    int row = unit >> 4, u = unit & 15;
    *(short8*)(&sX[row][u * 8]) =
        cvt8(io + (size_t)voxel_row(p, row) * 128 + u * 8);
  }
  __syncthreads();
  f32x4 acc[4][2];
#pragma unroll
  for (int mt = 0; mt < 4; ++mt) {
    acc[mt][0] = f32x4{0.f, 0.f, 0.f, 0.f};
    acc[mt][1] = f32x4{0.f, 0.f, 0.f, 0.f};
  }
#pragma unroll
  for (int ks = 0; ks < 4; ++ks) {
    short8 a[4];
#pragma unroll
    for (int mt = 0; mt < 4; ++mt)
      a[mt] = *(const short8*)(&sX[mt * 16 + l15][ks * 32 + lg * 8]);
#pragma unroll
    for (int nt = 0; nt < 2; ++nt) {
      int ntg = wave * 2 + nt;
      short8 b = *(const short8*)(wpk + ((size_t)(ntg * 4 + ks) * 64 + lane) * 8);
#pragma unroll
      for (int mt = 0; mt < 4; ++mt)
        acc[mt][nt] = __builtin_amdgcn_mfma_f32_16x16x32_bf16(a[mt], b, acc[mt][nt], 0, 0, 0);
    }
  }
#pragma unroll
  for (int nt = 0; nt < 2; ++nt) {
    int n = (wave * 2 + nt) * 16 + l15;
    float bv = bias[n];
#pragma unroll
    for (int mt = 0; mt < 4; ++mt)
#pragma unroll
      for (int j = 0; j < 4; ++j)
        io[(size_t)voxel_row(p, mt * 16 + lg * 4 + j) * 128 + n] = acc[mt][nt][j] + bv;
  }
}

}  // namespace

extern "C" void kernel_launch(void* const* d_in, const int* in_sizes, int n_in,
                              void* d_out, int out_size, void* d_ws, size_t ws_size,
                              hipStream_t stream) {
  (void)in_sizes; (void)n_in; (void)out_size; (void)ws_size;
  const float* x = (const float*)d_in[0];
  const float* w_qkv = (const float*)d_in[1];
  const float* b_qkv = (const float*)d_in[2];
  const float* w_o = (const float*)d_in[3];
  const float* b_o = (const float*)d_in[4];

  float* out = (float*)d_out;
  float* q = out + 4194304;
  float* k = q + 4194304;
  float* v = k + 4194304;

  float* qwin = (float*)d_ws;                 // 512*128 f32
  float* kwin = qwin + 65536;                 // 512*128 f32
  int* ridx = (int*)(kwin + 65536);           // 512*4 i32
  short* wpk_qkv = (short*)(ridx + 2048);     // 96 KB
  short* wpk_o = wpk_qkv + 49152;             // 32 KB
  short* vt = wpk_o + 16384;                  // 512*128*64 bf16 = 8 MB

  k_pack<<<96, 64, 0, stream>>>(w_qkv, wpk_qkv, 384);
  k_pack<<<32, 64, 0, stream>>>(w_o, wpk_o, 128);
  k_winmean<<<512, 256, 0, stream>>>(x, w_qkv, b_qkv, qwin, kwin);
  k_qkv<<<512, 256, 0, stream>>>(x, wpk_qkv, b_qkv, q, k, v, vt);
  k_route<<<512, 256, 0, stream>>>(qwin, kwin, ridx);
  k_attn<<<1024, 256, 0, stream>>>(q, k, vt, ridx, out);
  k_proj<<<512, 256, 0, stream>>>(out, wpk_o, b_o);
}